// Round 14
// baseline (6760.074 us; speedup 1.0000x reference)
//
#include <hip/hip_runtime.h>

#define TS    576
#define TC    288          // timesteps per l1/proj chunk (2 chunks; statics < 2 GiB)
#define HID   128
#define GT    512          // 4*HID
#define K0P   160          // 15 x (emb-folded) | 128 h0 | 17 zero pad
#define BB    8            // batch rows per block
#define NT    1024         // lstm kernels: 16 waves, 1 wg/CU (LDS-forced)
#define BNT   256          // proj kernel threads
#define BROWS 32           // proj rows per block
#define TS128 (TS*HID)

// prepped weights (k-major, gate-interleaved columns jn = unit*4 + gate)
__device__ float g_wt0[K0P * GT];
__device__ float g_b0[GT];
__device__ float g_wih1[HID * GT];
__device__ float g_whh1[HID * GT];
__device__ float g_b1[GT];
__device__ float g_out0[(size_t)2048 * TS * HID];   // 604 MB: out0[b][t][128]
__device__ float g_G1[(size_t)2048 * TC * GT];      // 1.21 GB: G1 chunk [b*TC+tc][512]
__device__ float g_h1[2048 * HID];                  // l1 h state across chunks
__device__ float g_c1[2048 * HID];                  // l1 c state across chunks

__global__ void prep_kernel(const float* __restrict__ W_emb, const float* __restrict__ b_emb,
                            const float* __restrict__ W_ih0, const float* __restrict__ W_hh0,
                            const float* __restrict__ b_ih0, const float* __restrict__ b_hh0,
                            const float* __restrict__ W_ih1, const float* __restrict__ W_hh1,
                            const float* __restrict__ b_ih1, const float* __restrict__ b_hh1)
{
    const int jo = blockIdx.x * blockDim.x + threadIdx.x;
    if (jo >= GT) return;
    const int g  = jo >> 7;         // gate 0..3 (i,f,g,o)
    const int u  = jo & 127;        // unit
    const int jn = (u << 2) | g;    // interleaved column

    for (int i = 0; i < 15; ++i) {
        float s = 0.f;
        for (int c = 0; c < 32; ++c) s = fmaf(W_ih0[jo*32 + c], W_emb[c*15 + i], s);
        g_wt0[i*GT + jn] = s;
    }
    for (int k = 0; k < HID; ++k) g_wt0[(15 + k)*GT + jn] = W_hh0[jo*HID + k];
    for (int k = 143; k < K0P; ++k) g_wt0[k*GT + jn] = 0.f;
    float bb = b_ih0[jo] + b_hh0[jo];
    for (int c = 0; c < 32; ++c) bb = fmaf(W_ih0[jo*32 + c], b_emb[c], bb);
    g_b0[jn] = bb;

    for (int k = 0; k < HID; ++k) g_wih1[k*GT + jn] = W_ih1[jo*HID + k];
    for (int k = 0; k < HID; ++k) g_whh1[k*GT + jn] = W_hh1[jo*HID + k];
    g_b1[jn] = b_ih1[jo] + b_hh1[jo];
}

// Fast activations: v_exp + v_rcp approx (err ~1e-6 << 4.66e-4 budget).
__device__ __forceinline__ float sigm(float v)   { return __builtin_amdgcn_rcpf(1.f + __expf(-v)); }
__device__ __forceinline__ float tanh_f(float v) { return 1.f - 2.f * __builtin_amdgcn_rcpf(1.f + __expf(2.f * v)); }

#define LD4(P_) (*(const float4*)(P_))
// macro params must never be named x/y/z/w/a/s
#define FMARC(A_, SV_, W_) \
    A_.x = fmaf(SV_, W_.x, A_.x); A_.y = fmaf(SV_, W_.y, A_.y); \
    A_.z = fmaf(SV_, W_.z, A_.z); A_.w = fmaf(SV_, W_.w, A_.w);

// ============================ Kernel A: layer-0 ============================
// Two-phase pipeline per step: phase A = GEMM(rows0-3,t) || update(rows4-7,t-1)
// || stage x(rows4-7,t); phase B = GEMM(rows4-7,t) || update(rows0-3,t) ||
// stage x(rows0-3,t+1). Update/stage run on dedicated threads concurrently
// with GEMM issue -> the ~5k-cyc/step serial update gap (r13 counters) hides.
__global__ void __attribute__((amdgpu_flat_work_group_size(NT, NT)))
lstm_l0(const float* __restrict__ x, float* __restrict__ out0)
{
    __shared__ float src0[BB][K0P];     // 5 KB: [15 x | 128 h | 17 pad] per row
    __shared__ float part[8][BB][GT];   // 128 KB -> 1 wg/CU

    const int tid  = threadIdx.x;
    const int cg   = tid & 127;
    const int q4   = cg << 2;
    const int ks   = tid >> 7;          // 0..7, wave-uniform
    const int row0 = blockIdx.x * BB;
    const int k0b  = ks * 20;

    const float* p0 = g_wt0 + (size_t)k0b * GT + q4;
#define DECLA(I_) const float4 wa##I_ = LD4(p0 + (I_)*GT);
    DECLA(0)  DECLA(1)  DECLA(2)  DECLA(3)  DECLA(4)
    DECLA(5)  DECLA(6)  DECLA(7)  DECLA(8)  DECLA(9)
    DECLA(10) DECLA(11) DECLA(12) DECLA(13) DECLA(14)
    DECLA(15) DECLA(16) DECLA(17) DECLA(18) DECLA(19)

    const float4 zz = make_float4(0.f, 0.f, 0.f, 0.f);
    const float4 i0 = (ks == 0) ? LD4(g_b0 + q4) : zz;

    // update role: tid<512 -> element (row, unit); handles 2 rows (ur4 and 4+ur4)
    const int ur4 = (tid >> 7) & 3;
    const int um  = tid & 127;
    float c_lo = 0.f, c_hi = 0.f;       // c for rows ur4 (lo) and 4+ur4 (hi)

    // x stager role: tid in [512, 572): 4 rows x 15 features per phase
    const bool xs = (tid >= 512 && tid < 572);
    const int  sx  = xs ? (tid - 512) : 0;
    const int  lr4 = sx / 15, li = sx - lr4 * 15;
    const float* xpl = x + (size_t)(row0 + lr4)     * (TS * 15) + li;  // rows 0-3
    const float* xph = x + (size_t)(row0 + 4 + lr4) * (TS * 15) + li;  // rows 4-7

    for (int i = tid; i < BB*K0P; i += NT) (&src0[0][0])[i] = 0.f;
    __syncthreads();
    if (xs) src0[lr4][li] = xpl[0];     // pre-stage x(0) rows 0-3
    __syncthreads();

    float* pp = &part[ks][0][0];

#define L0R(R_) { \
    const float* sp_ = &src0[R_][k0b]; \
    const float4 s0_ = LD4(sp_+0),  s1_ = LD4(sp_+4),  s2_ = LD4(sp_+8); \
    const float4 s3_ = LD4(sp_+12), s4_ = LD4(sp_+16); \
    float4 acc_ = i0; \
    FMARC(acc_, s0_.x, wa0)  FMARC(acc_, s0_.y, wa1)  FMARC(acc_, s0_.z, wa2)  FMARC(acc_, s0_.w, wa3)  \
    FMARC(acc_, s1_.x, wa4)  FMARC(acc_, s1_.y, wa5)  FMARC(acc_, s1_.z, wa6)  FMARC(acc_, s1_.w, wa7)  \
    FMARC(acc_, s2_.x, wa8)  FMARC(acc_, s2_.y, wa9)  FMARC(acc_, s2_.z, wa10) FMARC(acc_, s2_.w, wa11) \
    FMARC(acc_, s3_.x, wa12) FMARC(acc_, s3_.y, wa13) FMARC(acc_, s3_.z, wa14) FMARC(acc_, s3_.w, wa15) \
    FMARC(acc_, s4_.x, wa16) FMARC(acc_, s4_.y, wa17) FMARC(acc_, s4_.z, wa18) FMARC(acc_, s4_.w, wa19) \
    *(float4*)(pp + (R_)*GT + q4) = acc_; }

// update one element (ROW_, um) finishing step TU_; cell state C_
#define UPD0(ROW_, C_, TU_) { \
    const int ub_ = um << 2; \
    float4 gv_ = LD4(&part[0][ROW_][ub_]); \
    _Pragma("unroll") \
    for (int s_ = 1; s_ < 8; ++s_) { \
        const float4 p_ = LD4(&part[s_][ROW_][ub_]); \
        gv_.x += p_.x; gv_.y += p_.y; gv_.z += p_.z; gv_.w += p_.w; \
    } \
    const float iv_ = sigm(gv_.x), fv_ = sigm(gv_.y), ov_ = sigm(gv_.w); \
    const float gg_ = tanh_f(gv_.z); \
    C_ = fmaf(fv_, C_, iv_ * gg_); \
    const float hv_ = ov_ * tanh_f(C_); \
    src0[ROW_][15 + um] = hv_; \
    out0[(size_t)(row0 + (ROW_)) * TS128 + (size_t)(TU_) * HID + um] = hv_; }

    #pragma unroll 1
    for (int t = 0; t < TS; ++t) {
        // ---- phase A: GEMM rows0-3 (t) || update rows4-7 (t-1) || stage x rows4-7 (t)
        L0R(0) L0R(1) L0R(2) L0R(3)
        if (tid < 512) { if (t > 0) UPD0(4 + ur4, c_hi, t - 1) }
        else if (xs)   src0[4 + lr4][li] = xph[(size_t)t * 15];
        __syncthreads();
        // ---- phase B: GEMM rows4-7 (t) || update rows0-3 (t) || stage x rows0-3 (t+1)
        L0R(4) L0R(5) L0R(6) L0R(7)
        if (tid < 512) { UPD0(ur4, c_lo, t) }
        else if (xs && t + 1 < TS) src0[lr4][li] = xpl[(size_t)(t + 1) * 15];
        __syncthreads();
    }
    // epilogue: rows4-7 of final step
    if (tid < 512) UPD0(4 + ur4, c_hi, TS - 1)
}

// ============== Kernel B: parallel projection G1 = out0 @ W_ih1^T + b1 ==============
__global__ void __launch_bounds__(BNT)
proj1(int t0)
{
    __shared__ float At[HID][36];   // A-tile transposed [k][row], pad 36

    const int tid = threadIdx.x;
    const int rb  = blockIdx.x * BROWS;

    {
        const int row = tid >> 3;
        const int g   = rb + row;
        const int b   = g / TC;
        const int tc  = g - b * TC;
        const float* src = g_out0 + (size_t)(b * TS + t0 + tc) * HID;
        #pragma unroll
        for (int i = 0; i < 4; ++i) {
            const int kq = (tid & 7) + 8 * i;
            const float4 v = LD4(src + kq * 4);
            At[kq*4 + 0][row] = v.x;
            At[kq*4 + 1][row] = v.y;
            At[kq*4 + 2][row] = v.z;
            At[kq*4 + 3][row] = v.w;
        }
    }
    __syncthreads();

    const int q  = tid & 127;        // col quad
    const int r0 = (tid >> 7) * 16;  // row base (0 or 16)
    const float4 bq = LD4(g_b1 + q * 4);
    float4 a0=bq,a1=bq,a2=bq,a3=bq,a4=bq,a5=bq,a6=bq,a7=bq;
    float4 a8=bq,a9=bq,a10=bq,a11=bq,a12=bq,a13=bq,a14=bq,a15=bq;

    const float* wp = g_wih1 + q * 4;
    #pragma unroll 4
    for (int k = 0; k < HID; ++k) {
        const float4 wv = LD4(wp + (size_t)k * GT);
        const float4 h0_ = LD4(&At[k][r0 + 0]);
        const float4 h1_ = LD4(&At[k][r0 + 4]);
        const float4 h2_ = LD4(&At[k][r0 + 8]);
        const float4 h3_ = LD4(&At[k][r0 + 12]);
        FMARC(a0,  h0_.x, wv) FMARC(a1,  h0_.y, wv) FMARC(a2,  h0_.z, wv) FMARC(a3,  h0_.w, wv)
        FMARC(a4,  h1_.x, wv) FMARC(a5,  h1_.y, wv) FMARC(a6,  h1_.z, wv) FMARC(a7,  h1_.w, wv)
        FMARC(a8,  h2_.x, wv) FMARC(a9,  h2_.y, wv) FMARC(a10, h2_.z, wv) FMARC(a11, h2_.w, wv)
        FMARC(a12, h3_.x, wv) FMARC(a13, h3_.y, wv) FMARC(a14, h3_.z, wv) FMARC(a15, h3_.w, wv)
    }

    float* dst = g_G1 + (size_t)(rb + r0) * GT + q * 4;
#define STG(I_) *(float4*)(dst + (size_t)(I_) * GT) = a##I_;
    STG(0) STG(1) STG(2) STG(3) STG(4) STG(5) STG(6) STG(7)
    STG(8) STG(9) STG(10) STG(11) STG(12) STG(13) STG(14) STG(15)
}

// ============== Kernel C: recurrent layer-1 (W_hh1 only) + FC head ==============
// Same two-phase pipeline; staging role refills obuf (G1 slab) instead of x.
__global__ void __attribute__((amdgpu_flat_work_group_size(NT, NT)))
lstm_l1(int t0, int last,
        const float* __restrict__ W_fc1, const float* __restrict__ b_fc1,
        const float* __restrict__ W_fc2, const float* __restrict__ b_fc2,
        float* __restrict__ out)
{
    __shared__ float h1s[BB][HID];      //   4 KB
    __shared__ float obuf[BB][GT];      //  16 KB: G1[t] slab
    __shared__ float part[8][BB][GT];   // 128 KB -> 1 wg/CU (total 148 KB)

    const int tid  = threadIdx.x;
    const int cg   = tid & 127;
    const int q4   = cg << 2;
    const int ks   = tid >> 7;          // 0..7
    const int row0 = blockIdx.x * BB;
    const int k1b  = ks * 16;

    // persistent W_hh1 slice: 16 named float4 (64 VGPRs)
    const float* ph = g_whh1 + (size_t)k1b * GT + q4;
#define DECLB(I_) const float4 wb##I_ = LD4(ph + (I_)*GT);
    DECLB(0)  DECLB(1)  DECLB(2)  DECLB(3)
    DECLB(4)  DECLB(5)  DECLB(6)  DECLB(7)
    DECLB(8)  DECLB(9)  DECLB(10) DECLB(11)
    DECLB(12) DECLB(13) DECLB(14) DECLB(15)

    const float4 zz = make_float4(0.f, 0.f, 0.f, 0.f);

    const int ur4 = (tid >> 7) & 3;     // update role (tid<512)
    const int um  = tid & 127;
    float c_lo, c_hi;

    // G1 stager role: tid>=512, 512 threads = 4 rows x 128 quads per phase
    const int pr4 = (tid >> 7) & 3;     // for tid>=512: rows pr4 / 4+pr4
    const int pq  = tid & 127;
    const float* gpl = g_G1 + ((size_t)(row0 + pr4)     * TC) * GT + pq * 4;
    const float* gph = g_G1 + ((size_t)(row0 + 4 + pr4) * TC) * GT + pq * 4;

    // state init / restore
    if (t0 == 0) {
        c_lo = 0.f; c_hi = 0.f;
        h1s[tid >> 7][um] = 0.f;
        if (tid >= 512) h1s[4 + pr4][pq] = 0.f;   // rows 4-7 (redundant-safe)
    } else {
        h1s[tid >> 7][um] = g_h1[(row0 + (tid >> 7)) * HID + um];
        c_lo = g_c1[(row0 + ur4) * HID + um];
        c_hi = g_c1[(row0 + 4 + ur4) * HID + um];
    }
    __syncthreads();
    if (tid >= 512) *(float4*)(&obuf[pr4][pq << 2]) = LD4(gpl);   // pre-stage G1(0) rows0-3
    __syncthreads();

    float* pp = &part[ks][0][0];

#define L1R(R_) { \
    const float4 h0_ = LD4(&h1s[R_][k1b + 0]); \
    const float4 h1_ = LD4(&h1s[R_][k1b + 4]); \
    const float4 h2_ = LD4(&h1s[R_][k1b + 8]); \
    const float4 h3_ = LD4(&h1s[R_][k1b + 12]); \
    float4 acc_ = (ks == 0) ? LD4(&obuf[R_][q4]) : zz; \
    FMARC(acc_, h0_.x, wb0)  FMARC(acc_, h0_.y, wb1)  FMARC(acc_, h0_.z, wb2)  FMARC(acc_, h0_.w, wb3)  \
    FMARC(acc_, h1_.x, wb4)  FMARC(acc_, h1_.y, wb5)  FMARC(acc_, h1_.z, wb6)  FMARC(acc_, h1_.w, wb7)  \
    FMARC(acc_, h2_.x, wb8)  FMARC(acc_, h2_.y, wb9)  FMARC(acc_, h2_.z, wb10) FMARC(acc_, h2_.w, wb11) \
    FMARC(acc_, h3_.x, wb12) FMARC(acc_, h3_.y, wb13) FMARC(acc_, h3_.z, wb14) FMARC(acc_, h3_.w, wb15) \
    *(float4*)(pp + (R_)*GT + q4) = acc_; }

#define UPD1(ROW_, C_) { \
    const int ub_ = um << 2; \
    float4 gv_ = LD4(&part[0][ROW_][ub_]); \
    _Pragma("unroll") \
    for (int s_ = 1; s_ < 8; ++s_) { \
        const float4 p_ = LD4(&part[s_][ROW_][ub_]); \
        gv_.x += p_.x; gv_.y += p_.y; gv_.z += p_.z; gv_.w += p_.w; \
    } \
    const float iv_ = sigm(gv_.x), fv_ = sigm(gv_.y), ov_ = sigm(gv_.w); \
    const float gg_ = tanh_f(gv_.z); \
    C_ = fmaf(fv_, C_, iv_ * gg_); \
    h1s[ROW_][um] = ov_ * tanh_f(C_); }

    #pragma unroll 1
    for (int t = 0; t < TC; ++t) {
        // ---- phase A: GEMM rows0-3 (t) || update rows4-7 (t-1) || stage obuf rows4-7 (t)
        L1R(0) L1R(1) L1R(2) L1R(3)
        if (tid < 512) { if (t > 0) UPD1(4 + ur4, c_hi) }
        else *(float4*)(&obuf[4 + pr4][pq << 2]) = LD4(gph + (size_t)t * GT);
        __syncthreads();
        // ---- phase B: GEMM rows4-7 (t) || update rows0-3 (t) || stage obuf rows0-3 (t+1)
        L1R(4) L1R(5) L1R(6) L1R(7)
        if (tid < 512) { UPD1(ur4, c_lo) }
        else if (t + 1 < TC) *(float4*)(&obuf[pr4][pq << 2]) = LD4(gpl + (size_t)(t + 1) * GT);
        __syncthreads();
    }
    // epilogue: rows4-7 of final step
    if (tid < 512) UPD1(4 + ur4, c_hi)
    __syncthreads();

    // persist state for next chunk
    g_h1[(row0 + (tid >> 7)) * HID + um] = h1s[tid >> 7][um];
    if (tid < 512) {
        g_c1[(row0 + ur4) * HID + um]     = c_lo;
        g_c1[(row0 + 4 + ur4) * HID + um] = c_hi;
    }

    if (last) {
        // FC head: relu(h1 @ W_fc1^T + b_fc1) @ W_fc2^T + b_fc2
        if (tid < BB * 64) {
            const int rr = tid >> 6, u = tid & 63;
            float acc = b_fc1[u];
            #pragma unroll 8
            for (int k = 0; k < HID; ++k) acc = fmaf(h1s[rr][k], W_fc1[u*HID + k], acc);
            part[0][rr][u] = fmaxf(acc, 0.f);
        }
        __syncthreads();
        if (tid < BB) {
            float acc = b_fc2[0];
            #pragma unroll 8
            for (int u = 0; u < 64; ++u) acc = fmaf(part[0][tid][u], W_fc2[u], acc);
            out[row0 + tid] = acc;
        }
    }
}

extern "C" void kernel_launch(void* const* d_in, const int* in_sizes, int n_in,
                              void* d_out, int out_size, void* d_ws, size_t ws_size,
                              hipStream_t stream)
{
    const float* x     = (const float*)d_in[0];
    const float* W_emb = (const float*)d_in[1];
    const float* b_emb = (const float*)d_in[2];
    const float* W_ih0 = (const float*)d_in[3];
    const float* W_hh0 = (const float*)d_in[4];
    const float* b_ih0 = (const float*)d_in[5];
    const float* b_hh0 = (const float*)d_in[6];
    const float* W_ih1 = (const float*)d_in[7];
    const float* W_hh1 = (const float*)d_in[8];
    const float* b_ih1 = (const float*)d_in[9];
    const float* b_hh1 = (const float*)d_in[10];
    const float* W_fc1 = (const float*)d_in[11];
    const float* b_fc1 = (const float*)d_in[12];
    const float* W_fc2 = (const float*)d_in[13];
    const float* b_fc2 = (const float*)d_in[14];
    float* out = (float*)d_out;

    float* out0;
    hipGetSymbolAddress((void**)&out0, HIP_SYMBOL(g_out0));

    prep_kernel<<<2, 256, 0, stream>>>(W_emb, b_emb, W_ih0, W_hh0, b_ih0, b_hh0,
                                       W_ih1, W_hh1, b_ih1, b_hh1);
    lstm_l0<<<2048 / BB, NT, 0, stream>>>(x, out0);

    const int projBlocks = 2048 * TC / BROWS;   // 18432
    for (int c = 0; c < TS / TC; ++c) {
        proj1<<<projBlocks, BNT, 0, stream>>>(c * TC);
        lstm_l1<<<2048 / BB, NT, 0, stream>>>(c * TC, (c == TS / TC - 1) ? 1 : 0,
                                              W_fc1, b_fc1, W_fc2, b_fc2, out);
    }
}